// Round 3
// baseline (730.574 us; speedup 1.0000x reference)
//
#include <hip/hip_runtime.h>

typedef unsigned short u16;
typedef __attribute__((ext_vector_type(8))) short bf16x8;
typedef __attribute__((ext_vector_type(4))) float f32x4;
typedef __attribute__((ext_vector_type(16))) float f32x16;

__device__ __forceinline__ unsigned f2bf(float f) {
  unsigned u = __float_as_uint(f);
  return (u + 0x7fffu + ((u >> 16) & 1u)) >> 16;  // RNE fp32 -> bf16 bits
}

// async global->LDS, 16B per lane. LDS dest is wave-uniform base + lane*16.
__device__ __forceinline__ void async16(const u16* g, u16* l) {
  __builtin_amdgcn_global_load_lds(
      (const __attribute__((address_space(1))) void*)g,
      (__attribute__((address_space(3))) void*)l, 16, 0, 0);
}

// ---------------------------------------------------------------------------
// Small tiled MFMA GEMM (round-0, verified): C = A * Bt^T, m-major C.
// ---------------------------------------------------------------------------
template<int BN, bool AF32, bool CBF16>
__global__ __launch_bounds__(256, 2) void gemm_tile(
    const void* __restrict__ Av, const u16* __restrict__ Bt, void* __restrict__ Cv,
    int K, int lda, int ldb, int ldc,
    long long sA, long long sB, long long sC)
{
  constexpr int BM = 128, BK = 32, PAD = BK + 8;
  __shared__ __align__(16) u16 As[BM * PAD];
  __shared__ __align__(16) u16 Bs[BN * PAD];
  const int tid  = threadIdx.x;
  const int w    = tid >> 6;
  const int lane = tid & 63;
  const int l15  = lane & 15, quad = lane >> 4;
  const int m0 = blockIdx.x * BM, n0 = blockIdx.y * BN;
  const int bz = blockIdx.z;

  const u16* Bp = Bt + (size_t)sB * bz;

  f32x4 acc[2][BN / 16];
#pragma unroll
  for (int i = 0; i < 2; i++)
#pragma unroll
    for (int j = 0; j < BN / 16; j++)
#pragma unroll
      for (int r = 0; r < 4; r++) acc[i][j][r] = 0.f;

  for (int k0 = 0; k0 < K; k0 += BK) {
    __syncthreads();
    if constexpr (AF32) {
      const float* Af = (const float*)Av + (size_t)sA * bz;
      const int r = tid >> 3, c = (tid & 7) << 2;
#pragma unroll
      for (int rr = 0; rr < 4; rr++) {
        const int row = rr * 32 + r;
        const float4 v = *(const float4*)(Af + (size_t)(m0 + row) * lda + k0 + c);
        uint2 p;
        p.x = f2bf(v.x) | (f2bf(v.y) << 16);
        p.y = f2bf(v.z) | (f2bf(v.w) << 16);
        *(uint2*)(As + row * PAD + c) = p;
      }
    } else {
      const u16* Ah = (const u16*)Av + (size_t)sA * bz;
      const int r = tid >> 2, c = (tid & 3) << 3;
#pragma unroll
      for (int rr = 0; rr < 2; rr++) {
        const int row = rr * 64 + r;
        *(uint4*)(As + row * PAD + c) =
            *(const uint4*)(Ah + (size_t)(m0 + row) * lda + k0 + c);
      }
    }
    {
      const int r = tid >> 2, c = (tid & 3) << 3;
#pragma unroll
      for (int p = 0; p < BN / 64; p++) {
        const int n = p * 64 + r;
        *(uint4*)(Bs + n * PAD + c) =
            *(const uint4*)(Bp + (size_t)(n0 + n) * ldb + k0 + c);
      }
    }
    __syncthreads();
    const bf16x8 a0 = *(const bf16x8*)(As + (w * 32 + l15) * PAD + quad * 8);
    const bf16x8 a1 = *(const bf16x8*)(As + (w * 32 + 16 + l15) * PAD + quad * 8);
#pragma unroll
    for (int nt = 0; nt < BN / 16; nt++) {
      const bf16x8 bv = *(const bf16x8*)(Bs + (nt * 16 + l15) * PAD + quad * 8);
      acc[0][nt] = __builtin_amdgcn_mfma_f32_16x16x32_bf16(a0, bv, acc[0][nt], 0, 0, 0);
      acc[1][nt] = __builtin_amdgcn_mfma_f32_16x16x32_bf16(a1, bv, acc[1][nt], 0, 0, 0);
    }
  }
#pragma unroll
  for (int mt = 0; mt < 2; mt++)
#pragma unroll
    for (int nt = 0; nt < BN / 16; nt++)
#pragma unroll
      for (int rg = 0; rg < 4; rg++) {
        const size_t row = (size_t)m0 + w * 32 + mt * 16 + quad * 4 + rg;
        const size_t col = (size_t)n0 + nt * 16 + l15;
        if constexpr (CBF16)
          *((u16*)Cv + (size_t)sC * bz + row * ldc + col) = (u16)f2bf(acc[mt][nt][rg]);
        else
          *((float*)Cv + (size_t)sC * bz + row * ldc + col) = acc[mt][nt][rg];
      }
}

// ---------------------------------------------------------------------------
// Fused GCN layer gemm v3: C[b](2048x256) = A[b](2048x2048 fp32) @ Bt[b]^T,
// Bt (256x2048 bf16). Epilogue: +bias, LN over 256 feats, ReLU.
// BM=64, BN=256, BK=64. mfma_32x32x16. 4 waves side-by-side in n (64m x 64n).
// B tile in LDS, XOR-swizzled chunks (swizzle folded into async16 fetch).
// A fragments loaded fp32 straight from global, packed to bf16 in regs.
//   MEAN=false: store H bf16.  MEAN=true: column sums -> atomicAdd gcn.
// ---------------------------------------------------------------------------
template<bool MEAN>
__global__ __launch_bounds__(256, 2) void gcn_gemm(
    const float* __restrict__ A, const u16* __restrict__ Bt,
    const float* __restrict__ bias, const float* __restrict__ gam,
    const float* __restrict__ bet, u16* __restrict__ H, float* __restrict__ gcn)
{
  __shared__ __align__(16) u16 Bs[256 * 64];   // 32 KB, swizzled
  const int tid = threadIdx.x;
  const int w = tid >> 6, lane = tid & 63;
  const int l31 = lane & 31, half = lane >> 5;
  const int m0 = blockIdx.x * 64;
  const int bz = blockIdx.y;

  f32x16 acc[2][2];  // [mt][nt]
#pragma unroll
  for (int i = 0; i < 2; i++)
#pragma unroll
    for (int j = 0; j < 2; j++)
#pragma unroll
      for (int r = 0; r < 16; r++) acc[i][j][r] = 0.f;

  // B staging: thread covers physical 16B slot (p*256 + tid); swizzle
  // chunk_phys = chunk_log ^ (row&7) folded into the global fetch column.
  const int tn = tid >> 3;                    // row within 32-row chunk
  const int clog = (tid & 7) ^ (tn & 7);      // logical k-chunk to fetch
  const u16* Bg = Bt + (size_t)bz * 524288 + (size_t)tn * 2048 + clog * 8;
  u16* lB = Bs + tid * 8;

  // A fragment base: lane reads row m0 + mt*32 + l31, k-offset half*8
  const float* Ag = A + (size_t)bz * 4194304 + (size_t)(m0 + l31) * 2048 + half * 8;

  for (int k0 = 0; k0 < 2048; k0 += 64) {
    __syncthreads();
#pragma unroll
    for (int p = 0; p < 8; p++)
      async16(Bg + (size_t)p * 65536 + k0, lB + p * 2048);
    bf16x8 a[2][4];
#pragma unroll
    for (int mt = 0; mt < 2; mt++)
#pragma unroll
      for (int kk = 0; kk < 4; kk++) {
        const float* p = Ag + (size_t)mt * 65536 + k0 + kk * 16;
        const float4 v0 = *(const float4*)p;
        const float4 v1 = *(const float4*)(p + 4);
        union { bf16x8 v; uint4 u; } r;
        r.u.x = f2bf(v0.x) | (f2bf(v0.y) << 16);
        r.u.y = f2bf(v0.z) | (f2bf(v0.w) << 16);
        r.u.z = f2bf(v1.x) | (f2bf(v1.y) << 16);
        r.u.w = f2bf(v1.z) | (f2bf(v1.w) << 16);
        a[mt][kk] = r.v;
      }
    __syncthreads();
#pragma unroll
    for (int kk = 0; kk < 4; kk++)
#pragma unroll
      for (int nt = 0; nt < 2; nt++) {
        const int n = w * 64 + nt * 32 + l31;
        const int pc = (kk * 2 + half) ^ (l31 & 7);
        const bf16x8 b = *(const bf16x8*)(Bs + n * 64 + pc * 8);
        acc[0][nt] = __builtin_amdgcn_mfma_f32_32x32x16_bf16(a[0][kk], b, acc[0][nt], 0, 0, 0);
        acc[1][nt] = __builtin_amdgcn_mfma_f32_32x32x16_bf16(a[1][kk], b, acc[1][nt], 0, 0, 0);
      }
  }

  // ---- epilogue: +bias, LN over 256 cols per row, ReLU ----
  // C/D: col = w*64 + nt*32 + l31; row_local = (r&3) + 8*(r>>2) + 4*half.
  const int col0 = w * 64 + l31;
  const float b0 = bias[col0], b1 = bias[col0 + 32];
  float s2[2][16];
#pragma unroll
  for (int mt = 0; mt < 2; mt++)
#pragma unroll
    for (int r = 0; r < 16; r++) {
      acc[mt][0][r] += b0;
      acc[mt][1][r] += b1;
      s2[mt][r] = acc[mt][0][r] + acc[mt][1][r];
    }
#pragma unroll
  for (int off = 1; off <= 16; off <<= 1)
#pragma unroll
    for (int mt = 0; mt < 2; mt++)
#pragma unroll
      for (int r = 0; r < 16; r++) s2[mt][r] += __shfl_xor(s2[mt][r], off);

  float* sm = (float*)Bs;
  __syncthreads();                              // Bs reads done; reuse as scratch
  if (l31 == 0) {
#pragma unroll
    for (int mt = 0; mt < 2; mt++)
#pragma unroll
      for (int r = 0; r < 16; r++) {
        const int rl = (r & 3) + 8 * (r >> 2) + 4 * half;
        sm[w * 64 + mt * 32 + rl] = s2[mt][r];
      }
  }
  __syncthreads();
  if (tid < 64)
    sm[256 + tid] = (sm[tid] + sm[64 + tid] + sm[128 + tid] + sm[192 + tid]) * (1.f / 256.f);
  __syncthreads();
  float4 mu4[2][4];
#pragma unroll
  for (int mt = 0; mt < 2; mt++)
#pragma unroll
    for (int g = 0; g < 4; g++)
      mu4[mt][g] = *(const float4*)(sm + 256 + mt * 32 + g * 8 + 4 * half);

  float q2[2][16];
#pragma unroll
  for (int mt = 0; mt < 2; mt++)
#pragma unroll
    for (int r = 0; r < 16; r++) {
      const float mu = ((const float*)&mu4[mt][r >> 2])[r & 3];
      const float d0 = acc[mt][0][r] - mu, d1 = acc[mt][1][r] - mu;
      q2[mt][r] = d0 * d0 + d1 * d1;
    }
#pragma unroll
  for (int off = 1; off <= 16; off <<= 1)
#pragma unroll
    for (int mt = 0; mt < 2; mt++)
#pragma unroll
      for (int r = 0; r < 16; r++) q2[mt][r] += __shfl_xor(q2[mt][r], off);
  if (l31 == 0) {
#pragma unroll
    for (int mt = 0; mt < 2; mt++)
#pragma unroll
      for (int r = 0; r < 16; r++) {
        const int rl = (r & 3) + 8 * (r >> 2) + 4 * half;
        sm[w * 64 + mt * 32 + rl] = q2[mt][r];
      }
  }
  __syncthreads();
  if (tid < 64)
    sm[320 + tid] = rsqrtf(
        (sm[tid] + sm[64 + tid] + sm[128 + tid] + sm[192 + tid]) * (1.f / 256.f) + 1e-5f);
  __syncthreads();
  float4 iv4[2][4];
#pragma unroll
  for (int mt = 0; mt < 2; mt++)
#pragma unroll
    for (int g = 0; g < 4; g++)
      iv4[mt][g] = *(const float4*)(sm + 320 + mt * 32 + g * 8 + 4 * half);

  const float g0 = gam[col0], g1 = gam[col0 + 32];
  const float e0 = bet[col0], e1 = bet[col0 + 32];
  if constexpr (!MEAN) {
#pragma unroll
    for (int mt = 0; mt < 2; mt++)
#pragma unroll
      for (int r = 0; r < 16; r++) {
        const float mu = ((const float*)&mu4[mt][r >> 2])[r & 3];
        const float iv = ((const float*)&iv4[mt][r >> 2])[r & 3];
        const int rl = (r & 3) + 8 * (r >> 2) + 4 * half;
        const size_t row = (size_t)bz * 2048 + m0 + mt * 32 + rl;
        const float y0 = fmaxf((acc[mt][0][r] - mu) * iv * g0 + e0, 0.f);
        const float y1 = fmaxf((acc[mt][1][r] - mu) * iv * g1 + e1, 0.f);
        H[row * 256 + col0]      = (u16)f2bf(y0);
        H[row * 256 + col0 + 32] = (u16)f2bf(y1);
      }
  } else {
    float c0 = 0.f, c1 = 0.f;
#pragma unroll
    for (int mt = 0; mt < 2; mt++)
#pragma unroll
      for (int r = 0; r < 16; r++) {
        const float mu = ((const float*)&mu4[mt][r >> 2])[r & 3];
        const float iv = ((const float*)&iv4[mt][r >> 2])[r & 3];
        c0 += fmaxf((acc[mt][0][r] - mu) * iv * g0 + e0, 0.f);
        c1 += fmaxf((acc[mt][1][r] - mu) * iv * g1 + e1, 0.f);
      }
    c0 += __shfl_xor(c0, 32);
    c1 += __shfl_xor(c1, 32);
    if (half == 0) {
      atomicAdd(gcn + bz * 256 + col0, c0);
      atomicAdd(gcn + bz * 256 + col0 + 32, c1);
    }
  }
}

// fp32 -> bf16, 8 elems/thread
__global__ __launch_bounds__(256) void convert_bf16(const float* __restrict__ in,
                                                    u16* __restrict__ out, long long n8)
{
  const long long i = (long long)blockIdx.x * 256 + threadIdx.x;
  if (i >= n8) return;
  const float4 a = ((const float4*)in)[2 * i];
  const float4 b = ((const float4*)in)[2 * i + 1];
  uint4 r;
  r.x = f2bf(a.x) | (f2bf(a.y) << 16);
  r.y = f2bf(a.z) | (f2bf(a.w) << 16);
  r.z = f2bf(b.x) | (f2bf(b.y) << 16);
  r.w = f2bf(b.z) | (f2bf(b.w) << 16);
  ((uint4*)out)[i] = r;
}

__global__ __launch_bounds__(256) void transpose_bf16(const float* __restrict__ in,
                                                      u16* __restrict__ outp,
                                                      int rows, int cols)
{
  const int n = rows * cols;
  const int o = blockIdx.x * 256 + threadIdx.x;
  if (o < n) {
    const int c = o / rows, r = o - c * rows;
    outp[o] = (u16)f2bf(in[r * cols + c]);
  }
}

__global__ void zero_kernel(float* p, int n) {
  const int i = blockIdx.x * 256 + threadIdx.x;
  if (i < n) p[i] = 0.f;
}

__global__ __launch_bounds__(128) void final_kernel(
    const float* __restrict__ gcn, const float* __restrict__ gv,
    const float* __restrict__ Ws, const float* __restrict__ bs,
    const float* __restrict__ Wa, const float* __restrict__ ba,
    float* __restrict__ out)
{
  const int b = blockIdx.x, t = threadIdx.x;
  __shared__ float fused[274];
  fused[t] = gcn[b * 256 + t] * (1.f / 2048.f);
  fused[128 + t] = gcn[b * 256 + 128 + t] * (1.f / 2048.f);
  if (t < 18) fused[256 + t] = gv[b * 18 + t];
  __syncthreads();
  float acc = ba[t];
  for (int i = 0; i < 274; i++) acc = fmaf(fused[i], Wa[i * 128 + t], acc);
  out[16 + b * 128 + t] = acc;
  if (t < 64) {
    float p = 0.f;
    for (int i = t; i < 274; i += 64) p += fused[i] * Ws[i];
#pragma unroll
    for (int off = 32; off >= 1; off >>= 1) p += __shfl_xor(p, off);
    if (t == 0) out[b] = p + bs[0];
  }
}

extern "C" void kernel_launch(void* const* d_in, const int* in_sizes, int n_in,
                              void* d_out, int out_size, void* d_ws, size_t ws_size,
                              hipStream_t stream)
{
  const float* A   = (const float*)d_in[0];   // (16,2048,2048)
  const float* X   = (const float*)d_in[1];   // (16,2048,64)
  const float* GV  = (const float*)d_in[2];   // (16,18)
  const float* W1  = (const float*)d_in[3];   // (64,256)
  const float* b1  = (const float*)d_in[4];
  const float* g1  = (const float*)d_in[5];
  const float* be1 = (const float*)d_in[6];
  const float* W2  = (const float*)d_in[7];   // (256,256)
  const float* b2  = (const float*)d_in[8];
  const float* g2  = (const float*)d_in[9];
  const float* be2 = (const float*)d_in[10];
  const float* Ws  = (const float*)d_in[11];  // (274,1)
  const float* bs  = (const float*)d_in[12];
  const float* Wa  = (const float*)d_in[13];  // (274,128)
  const float* ba  = (const float*)d_in[14];
  float* out = (float*)d_out;
  (void)in_sizes; (void)n_in; (void)out_size; (void)ws_size;

  char* base = (char*)d_ws;
  u16*   Xbf = (u16*)(base + 0);           //  4,194,304 B (B,2048,64) bf16
  u16*   W1T = (u16*)(base + 4194304);     //     32,768 B (256,64)
  u16*   W2T = (u16*)(base + 4227072);     //    131,072 B (256,256)
  u16*   XWT = (u16*)(base + 4358144);     // 16,777,216 B (B,256,2048) = (X@W1)^T
  u16*   H1  = (u16*)(base + 21135360);    // 16,777,216 B (B,2048,256)
  u16*   HWT = (u16*)(base + 37912576);    // 16,777,216 B (B,256,2048) = (H1@W2)^T
  float* GCN = (float*)(base + 54689792);  //     16,384 B (16,256)

  zero_kernel<<<16, 256, 0, stream>>>(GCN, 4096);
  convert_bf16<<<1024, 256, 0, stream>>>(X, Xbf, 262144LL);
  transpose_bf16<<<64, 256, 0, stream>>>(W1, W1T, 64, 256);
  transpose_bf16<<<256, 256, 0, stream>>>(W2, W2T, 256, 256);

  // XWT = (X@W1)^T
  gemm_tile<128, false, true><<<dim3(2, 16, 16), 256, 0, stream>>>(
      W1T, Xbf, XWT, 64, 64, 64, 2048, 0LL, 131072LL, 524288LL);

  // H1 = relu(LN(A @ (X@W1) + b1))
  gcn_gemm<false><<<dim3(32, 16), 256, 0, stream>>>(A, XWT, b1, g1, be1, H1, nullptr);

  // HWT = (H1@W2)^T
  gemm_tile<128, false, true><<<dim3(2, 16, 16), 256, 0, stream>>>(
      W2T, H1, HWT, 256, 256, 256, 2048, 0LL, 524288LL, 524288LL);

  // GCN[b][c] = sum_nodes relu(LN(A @ (H1@W2) + b2))
  gcn_gemm<true><<<dim3(32, 16), 256, 0, stream>>>(A, HWT, b2, g2, be2, nullptr, GCN);

  final_kernel<<<16, 128, 0, stream>>>(GCN, GV, Ws, bs, Wa, ba, out);
}

// Round 4
// 599.132 us; speedup vs baseline: 1.2194x; 1.2194x over previous
//
#include <hip/hip_runtime.h>

typedef unsigned short u16;
typedef __attribute__((ext_vector_type(8))) short bf16x8;
typedef __attribute__((ext_vector_type(16))) float f32x16;

__device__ __forceinline__ unsigned f2bf(float f) {
  unsigned u = __float_as_uint(f);
  return (u + 0x7fffu + ((u >> 16) & 1u)) >> 16;  // RNE fp32 -> bf16 bits
}

// async global->LDS, 16B per lane. LDS dest is wave-uniform base + lane*16.
__device__ __forceinline__ void async16(const u16* g, u16* l) {
  __builtin_amdgcn_global_load_lds(
      (const __attribute__((address_space(1))) void*)g,
      (__attribute__((address_space(3))) void*)l, 16, 0, 0);
}

// ---------------------------------------------------------------------------
// Unified pipelined MFMA GEMM: C[bz](M x 256-slice) = A[bz] @ B[bz]^T
//   A: m-major k-contiguous bf16 (lda), B: n-major k-contiguous bf16 (ldb).
//   BM=64, BN=256, BK=64, mfma_32x32x16, 4 waves each 64m x 64n.
//   A double-buffered LDS (async16, 2 bufs), B single-buffered; manual
//   s_waitcnt vmcnt(2) keeps the A-prefetch in flight across the barrier.
//   XOR chunk swizzle (phys = log ^ (row&7)) folded into the global fetch.
// EPI: 0 = plain bf16 store; 1 = +bias,LN(256),ReLU -> bf16 store;
//      2 = +bias,LN(256),ReLU -> column sums atomicAdd into gcn.
// ---------------------------------------------------------------------------
template<int EPI>
__global__ __launch_bounds__(256, 2) void mm64(
    const u16* __restrict__ Aop, const u16* __restrict__ Bop,
    int K, int lda, int ldb, int ldc,
    long long sA, long long sB, long long sC,
    const float* __restrict__ bias, const float* __restrict__ gam,
    const float* __restrict__ bet, u16* __restrict__ Cb, float* __restrict__ gcn)
{
  __shared__ __align__(16) u16 As[2][64 * 64];   // 2 x 8 KB
  __shared__ __align__(16) u16 Bs[256 * 64];     // 32 KB
  const int tid = threadIdx.x;
  const int w = tid >> 6, lane = tid & 63, l31 = lane & 31, half = lane >> 5;
  const int m0 = blockIdx.x * 64, n0 = blockIdx.y * 256, bz = blockIdx.z;

  // staging map: call covers rows (grp*32 + tid/8), phys chunk tid&7,
  // logical chunk = phys ^ (row&7);  (grp*32 % 8 == 0 so row&7 = (tid>>3)&7)
  const int srow = tid >> 3;
  const int clog = (tid & 7) ^ (srow & 7);
  const u16* Ag = Aop + sA * bz + (size_t)(m0 + srow) * lda + clog * 8;
  const u16* Bg = Bop + sB * bz + (size_t)(n0 + srow) * ldb + clog * 8;

  f32x16 acc[2][2];
#pragma unroll
  for (int i = 0; i < 2; i++)
#pragma unroll
    for (int j = 0; j < 2; j++)
#pragma unroll
      for (int r = 0; r < 16; r++) acc[i][j][r] = 0.f;

  const int niter = K >> 6;
  // prologue: A(0) into buf 0
  async16(Ag, As[0] + tid * 8);
  async16(Ag + (size_t)32 * lda, As[0] + 2048 + tid * 8);

  for (int i = 0; i < niter; i++) {
    const int k0 = i << 6;
    __syncthreads();                       // drains A(i) (1-iter window) + lgkm
#pragma unroll
    for (int p = 0; p < 8; p++)            // B(i) -> Bs
      async16(Bg + (size_t)p * 32 * ldb + k0, Bs + p * 2048 + tid * 8);
    if (i + 1 < niter) {                   // A(i+1) prefetch, stays in flight
      u16* dst = As[(i + 1) & 1];
      async16(Ag + k0 + 64, dst + tid * 8);
      async16(Ag + (size_t)32 * lda + k0 + 64, dst + 2048 + tid * 8);
      __builtin_amdgcn_s_waitcnt(0x0F72);  // vmcnt(2): drain B(i), keep A(i+1)
    } else {
      __builtin_amdgcn_s_waitcnt(0x0F70);  // vmcnt(0)
    }
    __builtin_amdgcn_s_barrier();          // raw: B(i) visibility, no extra drain
    __asm__ volatile("" ::: "memory");     // keep ds_reads below the barrier
    const u16* Ab = As[i & 1];
#pragma unroll
    for (int kk = 0; kk < 4; kk++) {
      const int pc = ((kk * 2 + half) ^ (l31 & 7)) * 8;
      const bf16x8 a0 = *(const bf16x8*)(Ab + l31 * 64 + pc);
      const bf16x8 a1 = *(const bf16x8*)(Ab + (32 + l31) * 64 + pc);
      const int nr = (w * 64 + l31) * 64;
      const bf16x8 b0 = *(const bf16x8*)(Bs + nr + pc);
      const bf16x8 b1 = *(const bf16x8*)(Bs + nr + 32 * 64 + pc);
      acc[0][0] = __builtin_amdgcn_mfma_f32_32x32x16_bf16(a0, b0, acc[0][0], 0, 0, 0);
      acc[0][1] = __builtin_amdgcn_mfma_f32_32x32x16_bf16(a0, b1, acc[0][1], 0, 0, 0);
      acc[1][0] = __builtin_amdgcn_mfma_f32_32x32x16_bf16(a1, b0, acc[1][0], 0, 0, 0);
      acc[1][1] = __builtin_amdgcn_mfma_f32_32x32x16_bf16(a1, b1, acc[1][1], 0, 0, 0);
    }
  }

  __syncthreads();
  // C/D layout: col = w*64 + nt*32 + l31; row_local = (r&3) + 8*(r>>2) + 4*half.
  const int col0 = w * 64 + l31;

  if constexpr (EPI == 0) {
#pragma unroll
    for (int mt = 0; mt < 2; mt++)
#pragma unroll
      for (int r = 0; r < 16; r++) {
        const int rl = (r & 3) + 8 * (r >> 2) + 4 * half;
        const long long row = (long long)m0 + mt * 32 + rl;
        Cb[sC * bz + row * ldc + n0 + col0]      = (u16)f2bf(acc[mt][0][r]);
        Cb[sC * bz + row * ldc + n0 + col0 + 32] = (u16)f2bf(acc[mt][1][r]);
      }
    return;
  }

  // ---- LN epilogue (EPI 1/2): +bias, LN over 256 cols per row, ReLU ----
  const float b0 = bias[col0], b1 = bias[col0 + 32];
  float s2[2][16];
#pragma unroll
  for (int mt = 0; mt < 2; mt++)
#pragma unroll
    for (int r = 0; r < 16; r++) {
      acc[mt][0][r] += b0;
      acc[mt][1][r] += b1;
      s2[mt][r] = acc[mt][0][r] + acc[mt][1][r];
    }
#pragma unroll
  for (int off = 1; off <= 16; off <<= 1)
#pragma unroll
    for (int mt = 0; mt < 2; mt++)
#pragma unroll
      for (int r = 0; r < 16; r++) s2[mt][r] += __shfl_xor(s2[mt][r], off);

  float* sm = (float*)Bs;
  if (l31 == 0) {
#pragma unroll
    for (int mt = 0; mt < 2; mt++)
#pragma unroll
      for (int r = 0; r < 16; r++) {
        const int rl = (r & 3) + 8 * (r >> 2) + 4 * half;
        sm[w * 64 + mt * 32 + rl] = s2[mt][r];
      }
  }
  __syncthreads();
  if (tid < 64)
    sm[256 + tid] = (sm[tid] + sm[64 + tid] + sm[128 + tid] + sm[192 + tid]) * (1.f / 256.f);
  __syncthreads();
  float4 mu4[2][4];
#pragma unroll
  for (int mt = 0; mt < 2; mt++)
#pragma unroll
    for (int g = 0; g < 4; g++)
      mu4[mt][g] = *(const float4*)(sm + 256 + mt * 32 + g * 8 + 4 * half);

  float q2[2][16];
#pragma unroll
  for (int mt = 0; mt < 2; mt++)
#pragma unroll
    for (int r = 0; r < 16; r++) {
      const float mu = ((const float*)&mu4[mt][r >> 2])[r & 3];
      const float d0 = acc[mt][0][r] - mu, d1 = acc[mt][1][r] - mu;
      q2[mt][r] = d0 * d0 + d1 * d1;
    }
#pragma unroll
  for (int off = 1; off <= 16; off <<= 1)
#pragma unroll
    for (int mt = 0; mt < 2; mt++)
#pragma unroll
      for (int r = 0; r < 16; r++) q2[mt][r] += __shfl_xor(q2[mt][r], off);
  __syncthreads();
  if (l31 == 0) {
#pragma unroll
    for (int mt = 0; mt < 2; mt++)
#pragma unroll
      for (int r = 0; r < 16; r++) {
        const int rl = (r & 3) + 8 * (r >> 2) + 4 * half;
        sm[w * 64 + mt * 32 + rl] = q2[mt][r];
      }
  }
  __syncthreads();
  if (tid < 64)
    sm[320 + tid] = rsqrtf(
        (sm[tid] + sm[64 + tid] + sm[128 + tid] + sm[192 + tid]) * (1.f / 256.f) + 1e-5f);
  __syncthreads();
  float4 iv4[2][4];
#pragma unroll
  for (int mt = 0; mt < 2; mt++)
#pragma unroll
    for (int g = 0; g < 4; g++)
      iv4[mt][g] = *(const float4*)(sm + 320 + mt * 32 + g * 8 + 4 * half);

  const float g0 = gam[col0], g1 = gam[col0 + 32];
  const float e0 = bet[col0], e1 = bet[col0 + 32];
  if constexpr (EPI == 1) {
#pragma unroll
    for (int mt = 0; mt < 2; mt++)
#pragma unroll
      for (int r = 0; r < 16; r++) {
        const float mu = ((const float*)&mu4[mt][r >> 2])[r & 3];
        const float iv = ((const float*)&iv4[mt][r >> 2])[r & 3];
        const int rl = (r & 3) + 8 * (r >> 2) + 4 * half;
        const long long row = (long long)m0 + mt * 32 + rl;
        const float y0 = fmaxf((acc[mt][0][r] - mu) * iv * g0 + e0, 0.f);
        const float y1 = fmaxf((acc[mt][1][r] - mu) * iv * g1 + e1, 0.f);
        Cb[sC * bz + row * ldc + col0]      = (u16)f2bf(y0);
        Cb[sC * bz + row * ldc + col0 + 32] = (u16)f2bf(y1);
      }
  } else {
    float c0 = 0.f, c1 = 0.f;
#pragma unroll
    for (int mt = 0; mt < 2; mt++)
#pragma unroll
      for (int r = 0; r < 16; r++) {
        const float mu = ((const float*)&mu4[mt][r >> 2])[r & 3];
        const float iv = ((const float*)&iv4[mt][r >> 2])[r & 3];
        c0 += fmaxf((acc[mt][0][r] - mu) * iv * g0 + e0, 0.f);
        c1 += fmaxf((acc[mt][1][r] - mu) * iv * g1 + e1, 0.f);
      }
    c0 += __shfl_xor(c0, 32);
    c1 += __shfl_xor(c1, 32);
    if (half == 0) {
      atomicAdd(gcn + bz * 256 + col0, c0);
      atomicAdd(gcn + bz * 256 + col0 + 32, c1);
    }
  }
}

// fp32 -> bf16, 8 elems/thread
__global__ __launch_bounds__(256) void convert_bf16(const float* __restrict__ in,
                                                    u16* __restrict__ out, long long n8)
{
  const long long i = (long long)blockIdx.x * 256 + threadIdx.x;
  if (i >= n8) return;
  const float4 a = ((const float4*)in)[2 * i];
  const float4 b = ((const float4*)in)[2 * i + 1];
  uint4 r;
  r.x = f2bf(a.x) | (f2bf(a.y) << 16);
  r.y = f2bf(a.z) | (f2bf(a.w) << 16);
  r.z = f2bf(b.x) | (f2bf(b.y) << 16);
  r.w = f2bf(b.z) | (f2bf(b.w) << 16);
  ((uint4*)out)[i] = r;
}

__global__ __launch_bounds__(256) void transpose_bf16(const float* __restrict__ in,
                                                      u16* __restrict__ outp,
                                                      int rows, int cols)
{
  const int n = rows * cols;
  const int o = blockIdx.x * 256 + threadIdx.x;
  if (o < n) {
    const int c = o / rows, r = o - c * rows;
    outp[o] = (u16)f2bf(in[r * cols + c]);
  }
}

__global__ void zero_kernel(float* p, int n) {
  const int i = blockIdx.x * 256 + threadIdx.x;
  if (i < n) p[i] = 0.f;
}

// fused readout: fused=[gcn/2048, gv]; pred_y=fused@Ws+bs; pred_arr=fused@Wa+ba
__global__ __launch_bounds__(128) void final_kernel(
    const float* __restrict__ gcn, const float* __restrict__ gv,
    const float* __restrict__ Ws, const float* __restrict__ bs,
    const float* __restrict__ Wa, const float* __restrict__ ba,
    float* __restrict__ out)
{
  const int b = blockIdx.x, t = threadIdx.x;
  __shared__ float fused[274];
  fused[t] = gcn[b * 256 + t] * (1.f / 2048.f);
  fused[128 + t] = gcn[b * 256 + 128 + t] * (1.f / 2048.f);
  if (t < 18) fused[256 + t] = gv[b * 18 + t];
  __syncthreads();
  float acc = ba[t];
  for (int i = 0; i < 274; i++) acc = fmaf(fused[i], Wa[i * 128 + t], acc);
  out[16 + b * 128 + t] = acc;
  if (t < 64) {
    float p = 0.f;
    for (int i = t; i < 274; i += 64) p += fused[i] * Ws[i];
#pragma unroll
    for (int off = 32; off >= 1; off >>= 1) p += __shfl_xor(p, off);
    if (t == 0) out[b] = p + bs[0];
  }
}

extern "C" void kernel_launch(void* const* d_in, const int* in_sizes, int n_in,
                              void* d_out, int out_size, void* d_ws, size_t ws_size,
                              hipStream_t stream)
{
  const float* A   = (const float*)d_in[0];   // (16,2048,2048)
  const float* X   = (const float*)d_in[1];   // (16,2048,64)
  const float* GV  = (const float*)d_in[2];   // (16,18)
  const float* W1  = (const float*)d_in[3];   // (64,256)
  const float* b1  = (const float*)d_in[4];
  const float* g1  = (const float*)d_in[5];
  const float* be1 = (const float*)d_in[6];
  const float* W2  = (const float*)d_in[7];   // (256,256)
  const float* b2  = (const float*)d_in[8];
  const float* g2  = (const float*)d_in[9];
  const float* be2 = (const float*)d_in[10];
  const float* Ws  = (const float*)d_in[11];  // (274,1)
  const float* bs  = (const float*)d_in[12];
  const float* Wa  = (const float*)d_in[13];  // (274,128)
  const float* ba  = (const float*)d_in[14];
  float* out = (float*)d_out;
  (void)in_sizes; (void)n_in; (void)out_size; (void)ws_size;

  char* ws = (char*)d_ws;                  // needs 188,923,904 B (1 GiB observed)
  u16*   Abf = (u16*)(ws + 0);             // 134,217,728 B (16,2048,2048) bf16
  u16*   Xbf = (u16*)(ws + 134217728);     //   4,194,304 B (16,2048,64)
  u16*   W1T = (u16*)(ws + 138412032);     //      32,768 B (256,64)
  u16*   W2T = (u16*)(ws + 138444800);     //     131,072 B (256,256)
  u16*   XWT = (u16*)(ws + 138575872);     //  16,777,216 B (16,256,2048) = (X@W1)^T
  u16*   H1  = (u16*)(ws + 155353088);     //  16,777,216 B (16,2048,256)
  u16*   HWT = (u16*)(ws + 172130304);     //  16,777,216 B (16,256,2048) = (H1@W2)^T
  float* GCN = (float*)(ws + 188907520);   //      16,384 B (16,256)

  zero_kernel<<<16, 256, 0, stream>>>(GCN, 4096);
  convert_bf16<<<1024, 256, 0, stream>>>(X, Xbf, 262144LL);
  transpose_bf16<<<64, 256, 0, stream>>>(W1, W1T, 64, 256);
  transpose_bf16<<<256, 256, 0, stream>>>(W2, W2T, 256, 256);
  convert_bf16<<<32768, 256, 0, stream>>>(A, Abf, 8388608LL);

  // XWT = (X@W1)^T:  A-op = W1T (256x64), B-op = Xbf (nodes x 64)
  mm64<0><<<dim3(4, 8, 16), 256, 0, stream>>>(
      W1T, Xbf, 64, 64, 64, 2048, 0LL, 131072LL, 524288LL,
      nullptr, nullptr, nullptr, XWT, nullptr);

  // H1 = relu(LN(A @ (X@W1) + b1)):  A-op = Abf, B-op = XWT
  mm64<1><<<dim3(32, 1, 16), 256, 0, stream>>>(
      Abf, XWT, 2048, 2048, 2048, 256, 4194304LL, 524288LL, 524288LL,
      b1, g1, be1, H1, nullptr);

  // HWT = (H1@W2)^T:  A-op = W2T (256x256), B-op = H1 (nodes x 256)
  mm64<0><<<dim3(4, 8, 16), 256, 0, stream>>>(
      W2T, H1, 256, 256, 256, 2048, 0LL, 524288LL, 524288LL,
      nullptr, nullptr, nullptr, HWT, nullptr);

  // GCN[b][c] = sum_nodes relu(LN(A @ (H1@W2) + b2))
  mm64<2><<<dim3(32, 1, 16), 256, 0, stream>>>(
      Abf, HWT, 2048, 2048, 2048, 256, 4194304LL, 524288LL, 524288LL,
      b2, g2, be2, nullptr, GCN);

  final_kernel<<<16, 128, 0, stream>>>(GCN, GV, Ws, bs, Wa, ba, out);
}